// Round 5
// baseline (300.154 us; speedup 1.0000x reference)
//
#include <hip/hip_runtime.h>

// RWKV time mixing: LN -> token-shift mix -> 3x low-rank proj -> chunked scan
// -> output GEMM. B=4, T=2048, C=2048, R=256.
// Round 5: gemm_pipe now stages ONLY A through LDS (8-deep ring of 16KB
// tile-buffers, XOR-swizzled, 0-conflict); B fragments are loaded
// global->register direct (L2-resident weight panels), double-buffered one
// tile ahead; one vmcnt-gate + barrier per PAIR of K=32 tiles.

typedef __attribute__((ext_vector_type(8))) __bf16 bf16x8;
typedef __attribute__((ext_vector_type(4))) float f32x4;

static constexpr int Bb = 4, Tt = 2048, Cc = 2048, Rr = 256;
static constexpr int Mrows = Bb * Tt;      // 8192
static constexpr int NCH = 32, CLEN = 64;  // scan chunking

__device__ __forceinline__ unsigned short f2bf(float f) {
  union { float f; unsigned u; } a; a.f = f;
  unsigned r = (a.u + 0x7FFFu + ((a.u >> 16) & 1u)) >> 16;  // RNE
  return (unsigned short)r;
}
__device__ __forceinline__ float bf2f(unsigned short h) {
  union { unsigned u; float f; } a; a.u = ((unsigned)h) << 16;
  return a.f;
}

__device__ __forceinline__ void gload16(const void* g, void* l) {
  __builtin_amdgcn_global_load_lds(
      (const __attribute__((address_space(1))) void*)g,
      (__attribute__((address_space(3))) void*)l, 16, 0, 0);
}

// ---------------- weight prep ----------------------------------------------
__global__ void prep_weights(const float* __restrict__ wqa, const float* __restrict__ wka,
                             const float* __restrict__ wva, const float* __restrict__ wqb,
                             const float* __restrict__ wkb, const float* __restrict__ wvb,
                             const float* __restrict__ ow,  const float* __restrict__ td,
                             unsigned short* __restrict__ waT, unsigned short* __restrict__ wbT,
                             unsigned short* __restrict__ owT, float* __restrict__ decay,
                             float* __restrict__ decayL) {
  const int g = blockIdx.x * blockDim.x + threadIdx.x;
  const int stride = gridDim.x * blockDim.x;
  for (int i = g; i < 3 * Rr * Cc; i += stride) {
    int c = i & (Cc - 1); int jj = i >> 11; int p = jj >> 8; int r = jj & (Rr - 1);
    const float* w = (p == 0) ? wqa : ((p == 1) ? wka : wva);
    waT[i] = f2bf(w[(size_t)c * Rr + r]);
  }
  for (int i = g; i < 3 * Cc * Rr; i += stride) {
    int r = i & (Rr - 1); int d = (i >> 8) & (Cc - 1); int p = i >> 19;
    const float* w = (p == 0) ? wqb : ((p == 1) ? wkb : wvb);
    wbT[i] = f2bf(w[(size_t)r * Cc + d]);
  }
  for (int i = g; i < Cc * Cc; i += stride) owT[i] = f2bf(ow[i]);
  for (int i = g; i < Cc; i += stride) {
    float e = expf(td[i]);
    decay[i] = expf(-e);
    decayL[i] = expf(-(float)CLEN * e);
  }
}

// ---------------- fused LayerNorm + token-shift mix -------------------------
__global__ __launch_bounds__(256) void lnmix_kernel(
    const float* __restrict__ x, const float* __restrict__ gamma,
    const float* __restrict__ beta, unsigned short* __restrict__ mix) {
  const int m = blockIdx.x;
  const int t = m & (Tt - 1);
  const float* xr = x + (size_t)m * Cc;
  float s0 = 0.f, q0 = 0.f, s1 = 0.f, q1 = 0.f;
  float4 cur[2], prv[2];
#pragma unroll
  for (int r = 0; r < 2; ++r) {
    int i = threadIdx.x + r * 256;
    float4 v = ((const float4*)xr)[i];
    cur[r] = v;
    s0 += v.x + v.y + v.z + v.w;
    q0 += v.x * v.x + v.y * v.y + v.z * v.z + v.w * v.w;
  }
  if (t > 0) {
    const float* xp = xr - Cc;
#pragma unroll
    for (int r = 0; r < 2; ++r) {
      int i = threadIdx.x + r * 256;
      float4 v = ((const float4*)xp)[i];
      prv[r] = v;
      s1 += v.x + v.y + v.z + v.w;
      q1 += v.x * v.x + v.y * v.y + v.z * v.z + v.w * v.w;
    }
  }
#pragma unroll
  for (int off = 32; off; off >>= 1) {
    s0 += __shfl_down(s0, off); q0 += __shfl_down(q0, off);
    s1 += __shfl_down(s1, off); q1 += __shfl_down(q1, off);
  }
  __shared__ float red[4][4];
  __shared__ float bc[4];
  if ((threadIdx.x & 63) == 0) {
    int w = threadIdx.x >> 6;
    red[w][0] = s0; red[w][1] = q0; red[w][2] = s1; red[w][3] = q1;
  }
  __syncthreads();
  if (threadIdx.x == 0) {
    float a0 = 0, b0 = 0, a1 = 0, b1 = 0;
    for (int w = 0; w < 4; ++w) { a0 += red[w][0]; b0 += red[w][1]; a1 += red[w][2]; b1 += red[w][3]; }
    float mu0 = a0 * (1.f / Cc);
    bc[0] = mu0; bc[1] = rsqrtf(b0 * (1.f / Cc) - mu0 * mu0 + 1e-5f);
    float mu1 = a1 * (1.f / Cc);
    bc[2] = mu1; bc[3] = rsqrtf(b1 * (1.f / Cc) - mu1 * mu1 + 1e-5f);
  }
  __syncthreads();
  const float mu0 = bc[0], rs0 = bc[1], mu1 = bc[2], rs1 = bc[3];
#pragma unroll
  for (int r = 0; r < 2; ++r) {
    int i = threadIdx.x + r * 256;
    float4 g = ((const float4*)gamma)[i];
    float4 bb = ((const float4*)beta)[i];
    float4 v = cur[r];
    float mx = (v.x - mu0) * rs0 * g.x + bb.x;
    float my = (v.y - mu0) * rs0 * g.y + bb.y;
    float mz = (v.z - mu0) * rs0 * g.z + bb.z;
    float mw = (v.w - mu0) * rs0 * g.w + bb.w;
    if (t > 0) {
      float4 u = prv[r];
      mx = 0.5f * (mx + (u.x - mu1) * rs1 * g.x + bb.x);
      my = 0.5f * (my + (u.y - mu1) * rs1 * g.y + bb.y);
      mz = 0.5f * (mz + (u.z - mu1) * rs1 * g.z + bb.z);
      mw = 0.5f * (mw + (u.w - mu1) * rs1 * g.w + bb.w);
    } else {
      mx *= 0.5f; my *= 0.5f; mz *= 0.5f; mw *= 0.5f;
    }
    ushort4 o;
    o.x = f2bf(mx); o.y = f2bf(my); o.z = f2bf(mz); o.w = f2bf(mw);
    ((ushort4*)mix)[(size_t)m * 512 + i] = o;
  }
}

// ---------------- 256^2 GEMM: A via LDS ring-8, B register-direct ----------
// 512 threads = 8 waves (2 M x 4 N); wave tile 128x64; acc[8][4] f32x4.
// LDS: 8 ring buffers x (A 256x32 bf16 = 16KB) = 128 KiB, XOR-swizzled
// (slot s of row r at s ^ ((r>>1)&3); linear gload_lds dest + pre-swizzled
// global source col; 0 bank conflicts, verified r3).
// B fragments: 4 bf16x8 per wave per tile, loaded global->reg (L2-resident
// weight panel), double-buffered bcur/bnxt one tile ahead; compiler-inserted
// vmcnt waits on B regs also (in-order vmcnt retirement) guarantee the older
// A-stage gloads have landed. One gate+barrier per PAIR of tiles: pair P
// stages pair P+2's A (bufs reused 2 barriers later -> safe).
template <bool STORE_BF16, bool ADD_BIAS>
__global__ __launch_bounds__(512, 2) void gemm_pipe(
    const unsigned short* __restrict__ A0p, long lda, long aStrideP,
    const unsigned short* __restrict__ B0p, long ldb, long bStrideP,
    void* c0, void* c1, void* c2, long ldc, int K,
    const float* __restrict__ bias, int nbx, int nby) {
  __shared__ unsigned short lds[8 * 8192];
  const int tid = threadIdx.x;
  const int nwg = gridDim.x;
  const int id = blockIdx.x;
  const int q = nwg >> 3;
  const int swz = (id & 7) * q + (id >> 3);
  const int per = nbx * nby;
  const int p = swz / per;
  const int r2 = swz - p * per;
  // column-major tile order: an XCD chunk shares one B n-panel (L2-resident)
  const int nblk = r2 / nby;
  const int mblk = r2 - nblk * nby;
  const unsigned short* A  = A0p + (long)p * aStrideP;
  const unsigned short* Bt = B0p + (long)p * bStrideP;
  void* Cout = (p == 0) ? c0 : (p == 1 ? c1 : c2);
  const long m0 = (long)mblk * 256, n0 = (long)nblk * 256;

  const int lane = tid & 63, wid = tid >> 6;
  const int wm = wid >> 2, wn = wid & 3;
  const int fr = lane & 15, fq = lane >> 4;

  // A staging: thread covers rows tid>>2 and (tid>>2)+128, linear LDS dest,
  // source col pre-swizzled: s_src = (tid&3) ^ ((row>>1)&3).
  const int srow = tid >> 2;
  const int s_src = (tid & 3) ^ ((tid >> 3) & 3);
  const unsigned short* Ag = A + (m0 + srow) * lda + s_src * 8;

  // A read side: logical slot fq of row (..+fr) lives at slot fq ^ ((fr>>1)&3)
  const int swzs = fq ^ ((fr >> 1) & 3);
  const unsigned short* aBase = &lds[(wm * 128 + fr) * 32 + swzs * 8];

  // B direct: wave's fragment rows n0 + wn*64 + j*16 + fr, cols t*32 + fq*8
  const unsigned short* Bgp = Bt + (n0 + wn * 64 + fr) * ldb + fq * 8;

  f32x4 acc[8][4];
#pragma unroll
  for (int i = 0; i < 8; ++i)
#pragma unroll
    for (int j = 0; j < 4; ++j) acc[i][j] = (f32x4){0.f, 0.f, 0.f, 0.f};

  const int NT = K >> 5;   // K=32 tiles; NT even for all our shapes
  const int NP = NT >> 1;

  auto stageA = [&](int t) {
    unsigned short* d = &lds[(t & 7) * 8192 + tid * 8];
    const long kt = (long)t * 32;
    gload16(Ag + kt, d);
    gload16(Ag + 128 * lda + kt, d + 4096);
  };
  bf16x8 bcur[4], bnxt[4];
  auto loadB = [&](bf16x8* dst, int t) {
    const long co = (long)t * 32;
#pragma unroll
    for (int j = 0; j < 4; ++j)
      dst[j] = *(const bf16x8*)(Bgp + (long)(j * 16) * ldb + co);
  };

  // prologue: stage A pairs 0,1 (tiles 0..3), B fragment for tile 0
  stageA(0); stageA(1); stageA(2); stageA(3);
  loadB(bcur, 0);

  for (int pr = 0; pr < NP; ++pr) {
    const int t0 = 2 * pr, t1 = 2 * pr + 1;
    asm volatile("s_waitcnt vmcnt(8)" ::: "memory");
    __builtin_amdgcn_s_barrier();
    __builtin_amdgcn_sched_barrier(0);  // keep ds_reads below the barrier

    // ---- even tile: MFMA with bcur, prefetch bnxt=B(t1), stage pair+2 ----
    {
      const unsigned short* ab = aBase + (t0 & 7) * 8192;
      bf16x8 af[8];
#pragma unroll
      for (int i = 0; i < 8; ++i) af[i] = *(const bf16x8*)(ab + i * 512);
      loadB(bnxt, t1);
      if (t0 + 4 < NT) { stageA(t0 + 4); stageA(t0 + 5); }
      __builtin_amdgcn_s_setprio(1);
#pragma unroll
      for (int i = 0; i < 8; ++i)
#pragma unroll
        for (int j = 0; j < 4; ++j)
          acc[i][j] = __builtin_amdgcn_mfma_f32_16x16x32_bf16(af[i], bcur[j], acc[i][j], 0, 0, 0);
      __builtin_amdgcn_s_setprio(0);
    }
    // ---- odd tile: MFMA with bnxt, prefetch bcur=B(t1+1) ----
    {
      const unsigned short* ab = aBase + (t1 & 7) * 8192;
      bf16x8 af[8];
#pragma unroll
      for (int i = 0; i < 8; ++i) af[i] = *(const bf16x8*)(ab + i * 512);
      if (t1 + 1 < NT) loadB(bcur, t1 + 1);
      __builtin_amdgcn_s_setprio(1);
#pragma unroll
      for (int i = 0; i < 8; ++i)
#pragma unroll
        for (int j = 0; j < 4; ++j)
          acc[i][j] = __builtin_amdgcn_mfma_f32_16x16x32_bf16(af[i], bnxt[j], acc[i][j], 0, 0, 0);
      __builtin_amdgcn_s_setprio(0);
    }
  }

#pragma unroll
  for (int j = 0; j < 4; ++j) {
    const long col = n0 + wn * 64 + j * 16 + fr;
    const float bv = ADD_BIAS ? bias[col] : 0.0f;
#pragma unroll
    for (int i = 0; i < 8; ++i) {
      const long row0 = m0 + wm * 128 + i * 16 + fq * 4;
#pragma unroll
      for (int r = 0; r < 4; ++r) {
        float val = acc[i][j][r] + bv;
        if (STORE_BF16)
          ((unsigned short*)Cout)[(row0 + r) * ldc + col] = f2bf(val);
        else
          ((float*)Cout)[(row0 + r) * ldc + col] = val;
      }
    }
  }
}

// ---------------- split-K combine for G1 ------------------------------------
__global__ void addcvt_kernel(const float* __restrict__ p0, const float* __restrict__ p1,
                              unsigned short* __restrict__ o, int n4) {
  for (int i = blockIdx.x * blockDim.x + threadIdx.x; i < n4; i += gridDim.x * blockDim.x) {
    float4 a = ((const float4*)p0)[i];
    float4 b = ((const float4*)p1)[i];
    ushort4 r;
    r.x = f2bf(a.x + b.x); r.y = f2bf(a.y + b.y);
    r.z = f2bf(a.z + b.z); r.w = f2bf(a.w + b.w);
    ((ushort4*)o)[i] = r;
  }
}

// ---------------- chunked scan ---------------------------------------------
__global__ void scan_phaseA(const unsigned short* __restrict__ k, const unsigned short* __restrict__ v,
                            const float* __restrict__ decay, float* __restrict__ hend) {
  const int g = blockIdx.x * 256 + threadIdx.x;
  const int c = g & (Cc - 1);
  const int j = (g >> 11) & (NCH - 1);
  const int b = g >> 16;
  const float d = decay[c];
  size_t base = ((size_t)(b * Tt + j * CLEN)) * Cc + c;
  float h = 0.f;
#pragma unroll 8
  for (int s = 0; s < CLEN; ++s) {
    size_t idx = base + (size_t)s * Cc;
    float kv = bf2f(k[idx]) * bf2f(v[idx]);
    h = fmaf(d, h, kv);
  }
  hend[(size_t)(b * NCH + j) * Cc + c] = h;
}

__global__ void scan_combine(const float* __restrict__ hend, const float* __restrict__ h0,
                             const float* __restrict__ decayL, float* __restrict__ Hin,
                             float* __restrict__ hfinal) {
  const int g = blockIdx.x * 256 + threadIdx.x;
  const int c = g & (Cc - 1);
  float H = h0[g];
  const float dl = decayL[c];
  const int b = g >> 11;
  for (int j = 0; j < NCH; ++j) {
    size_t idx = (size_t)(b * NCH + j) * Cc + c;
    Hin[idx] = H;
    H = fmaf(dl, H, hend[idx]);
  }
  hfinal[g] = H;
}

__global__ void scan_phaseB(const unsigned short* __restrict__ q, const unsigned short* __restrict__ k,
                            const unsigned short* __restrict__ v, const float* __restrict__ decay,
                            const float* __restrict__ Hin, unsigned short* __restrict__ ys) {
  const int g = blockIdx.x * 256 + threadIdx.x;
  const int c = g & (Cc - 1);
  const int j = (g >> 11) & (NCH - 1);
  const int b = g >> 16;
  const float d = decay[c];
  float h = Hin[(size_t)(b * NCH + j) * Cc + c];
  size_t base = ((size_t)(b * Tt + j * CLEN)) * Cc + c;
#pragma unroll 4
  for (int s = 0; s < CLEN; ++s) {
    size_t idx = base + (size_t)s * Cc;
    float kv = bf2f(k[idx]) * bf2f(v[idx]);
    h = fmaf(d, h, kv);
    float qq = bf2f(q[idx]);
    float sg = 1.f / (1.f + expf(-qq));
    ys[idx] = f2bf(sg * h);
  }
}

// ---------------- launch ----------------------------------------------------
extern "C" void kernel_launch(void* const* d_in, const int* in_sizes, int n_in,
                              void* d_out, int out_size, void* d_ws, size_t ws_size,
                              hipStream_t stream) {
  const float* x   = (const float*)d_in[0];
  const float* h0  = (const float*)d_in[1];
  const float* gam = (const float*)d_in[2];
  const float* bet = (const float*)d_in[3];
  const float* wqa = (const float*)d_in[4];
  const float* wqb = (const float*)d_in[5];
  const float* wka = (const float*)d_in[6];
  const float* wkb = (const float*)d_in[7];
  const float* wva = (const float*)d_in[8];
  const float* wvb = (const float*)d_in[9];
  const float* ow  = (const float*)d_in[10];
  const float* ob  = (const float*)d_in[11];
  const float* td  = (const float*)d_in[12];
  float* out = (float*)d_out;

  char* ws = (char*)d_ws;
  unsigned short* waT   = (unsigned short*)(ws + 0);          //  3,145,728
  unsigned short* wbT   = (unsigned short*)(ws + 3145728);    //  3,145,728
  unsigned short* owT   = (unsigned short*)(ws + 6291456);    //  8,388,608
  float*          decay = (float*)(ws + 14680064);
  float*          decayL= (float*)(ws + 14688256);
  unsigned short* mixb  = (unsigned short*)(ws + 14761984);   // 33,554,432 (reused as ys)
  unsigned short* tmp   = (unsigned short*)(ws + 48316416);   // 12,582,912
  unsigned short* vp    = (unsigned short*)(ws + 60899328);   // 33,554,432
  float*          hend  = (float*)(ws + 94453760);
  float*          Hin   = (float*)(ws + 95502336);
  // staged in d_out (dead before overwritten): G1 f32 partials, then q,k bf16
  float* P0 = (float*)d_out;                                  // 25.2 MB
  float* P1 = P0 + (size_t)Mrows * 768;                       // 25.2 MB
  unsigned short* qp = (unsigned short*)d_out;
  unsigned short* kp = qp + (size_t)Mrows * Cc;
  float* hfinal = out + (size_t)Mrows * Cc;
  unsigned short* ysb = mixb;

  prep_weights<<<1024, 256, 0, stream>>>(wqa, wka, wva, wqb, wkb, wvb, ow, td,
                                         waT, wbT, owT, decay, decayL);
  lnmix_kernel<<<Mrows, 256, 0, stream>>>(x, gam, bet, mixb);

  // G1 split-K x2: P_p[8192][768] = mix[:, p*1024:(p+1)*1024] @ waT_half  (192 blocks)
  gemm_pipe<false, false><<<192, 512, 0, stream>>>(
      mixb, Cc, 1024, waT, Cc, 1024,
      P0, P1, nullptr, 768, 1024, nullptr, 3, 32);
  addcvt_kernel<<<1024, 256, 0, stream>>>(P0, P1, tmp, Mrows * 768 / 4);

  // G2 grouped: q/k/v[8192][2048] = tmp_p @ w_b_p   (768 blocks)
  gemm_pipe<true, false><<<8 * 32 * 3, 512, 0, stream>>>(
      tmp, 768, 256, wbT, Rr, (long)Cc * Rr,
      qp, kp, vp, Cc, Rr, nullptr, 8, 32);

  scan_phaseA<<<(Bb * NCH * Cc) / 256, 256, 0, stream>>>(kp, vp, decay, hend);
  scan_combine<<<(Bb * Cc) / 256, 256, 0, stream>>>(hend, h0, decayL, Hin, hfinal);
  scan_phaseB<<<(Bb * NCH * Cc) / 256, 256, 0, stream>>>(qp, kp, vp, decay, Hin, ysb);

  // Gout: out = ys @ out_w^T + out_b   (256 blocks)
  gemm_pipe<false, true><<<8 * 32, 512, 0, stream>>>(
      ysb, Cc, 0, owT, Cc, 0,
      out, out, out, Cc, Cc, ob, 8, 32);
}

// Round 6
// 244.509 us; speedup vs baseline: 1.2276x; 1.2276x over previous
//
#include <hip/hip_runtime.h>

// RWKV time mixing: LN -> token-shift mix -> 3x low-rank proj -> chunked scan
// -> output GEMM. B=4, T=2048, C=2048, R=256.
// Round 6: revert r5's B-register-direct (FETCH 3x regression). gemm_pipe is
// back to A+B-via-LDS with counted vmcnt, but reshaped for 2 blocks/CU:
// 256-thread blocks (4 waves, 2Mx2N), tile 256x128, BK=32, ring-3 (72KB LDS).
// Two resident blocks per CU cover each other's barrier/vmcnt stalls.

typedef __attribute__((ext_vector_type(8))) __bf16 bf16x8;
typedef __attribute__((ext_vector_type(4))) float f32x4;

static constexpr int Bb = 4, Tt = 2048, Cc = 2048, Rr = 256;
static constexpr int Mrows = Bb * Tt;      // 8192
static constexpr int NCH = 32, CLEN = 64;  // scan chunking

__device__ __forceinline__ unsigned short f2bf(float f) {
  union { float f; unsigned u; } a; a.f = f;
  unsigned r = (a.u + 0x7FFFu + ((a.u >> 16) & 1u)) >> 16;  // RNE
  return (unsigned short)r;
}
__device__ __forceinline__ float bf2f(unsigned short h) {
  union { unsigned u; float f; } a; a.u = ((unsigned)h) << 16;
  return a.f;
}

__device__ __forceinline__ void gload16(const void* g, void* l) {
  __builtin_amdgcn_global_load_lds(
      (const __attribute__((address_space(1))) void*)g,
      (__attribute__((address_space(3))) void*)l, 16, 0, 0);
}

// ---------------- weight prep ----------------------------------------------
__global__ void prep_weights(const float* __restrict__ wqa, const float* __restrict__ wka,
                             const float* __restrict__ wva, const float* __restrict__ wqb,
                             const float* __restrict__ wkb, const float* __restrict__ wvb,
                             const float* __restrict__ ow,  const float* __restrict__ td,
                             unsigned short* __restrict__ waT, unsigned short* __restrict__ wbT,
                             unsigned short* __restrict__ owT, float* __restrict__ decay,
                             float* __restrict__ decayL) {
  const int g = blockIdx.x * blockDim.x + threadIdx.x;
  const int stride = gridDim.x * blockDim.x;
  for (int i = g; i < 3 * Rr * Cc; i += stride) {
    int c = i & (Cc - 1); int jj = i >> 11; int p = jj >> 8; int r = jj & (Rr - 1);
    const float* w = (p == 0) ? wqa : ((p == 1) ? wka : wva);
    waT[i] = f2bf(w[(size_t)c * Rr + r]);
  }
  for (int i = g; i < 3 * Cc * Rr; i += stride) {
    int r = i & (Rr - 1); int d = (i >> 8) & (Cc - 1); int p = i >> 19;
    const float* w = (p == 0) ? wqb : ((p == 1) ? wkb : wvb);
    wbT[i] = f2bf(w[(size_t)r * Cc + d]);
  }
  for (int i = g; i < Cc * Cc; i += stride) owT[i] = f2bf(ow[i]);
  for (int i = g; i < Cc; i += stride) {
    float e = expf(td[i]);
    decay[i] = expf(-e);
    decayL[i] = expf(-(float)CLEN * e);
  }
}

// ---------------- fused LayerNorm + token-shift mix -------------------------
__global__ __launch_bounds__(256) void lnmix_kernel(
    const float* __restrict__ x, const float* __restrict__ gamma,
    const float* __restrict__ beta, unsigned short* __restrict__ mix) {
  const int m = blockIdx.x;
  const int t = m & (Tt - 1);
  const float* xr = x + (size_t)m * Cc;
  float s0 = 0.f, q0 = 0.f, s1 = 0.f, q1 = 0.f;
  float4 cur[2], prv[2];
#pragma unroll
  for (int r = 0; r < 2; ++r) {
    int i = threadIdx.x + r * 256;
    float4 v = ((const float4*)xr)[i];
    cur[r] = v;
    s0 += v.x + v.y + v.z + v.w;
    q0 += v.x * v.x + v.y * v.y + v.z * v.z + v.w * v.w;
  }
  if (t > 0) {
    const float* xp = xr - Cc;
#pragma unroll
    for (int r = 0; r < 2; ++r) {
      int i = threadIdx.x + r * 256;
      float4 v = ((const float4*)xp)[i];
      prv[r] = v;
      s1 += v.x + v.y + v.z + v.w;
      q1 += v.x * v.x + v.y * v.y + v.z * v.z + v.w * v.w;
    }
  }
#pragma unroll
  for (int off = 32; off; off >>= 1) {
    s0 += __shfl_down(s0, off); q0 += __shfl_down(q0, off);
    s1 += __shfl_down(s1, off); q1 += __shfl_down(q1, off);
  }
  __shared__ float red[4][4];
  __shared__ float bc[4];
  if ((threadIdx.x & 63) == 0) {
    int w = threadIdx.x >> 6;
    red[w][0] = s0; red[w][1] = q0; red[w][2] = s1; red[w][3] = q1;
  }
  __syncthreads();
  if (threadIdx.x == 0) {
    float a0 = 0, b0 = 0, a1 = 0, b1 = 0;
    for (int w = 0; w < 4; ++w) { a0 += red[w][0]; b0 += red[w][1]; a1 += red[w][2]; b1 += red[w][3]; }
    float mu0 = a0 * (1.f / Cc);
    bc[0] = mu0; bc[1] = rsqrtf(b0 * (1.f / Cc) - mu0 * mu0 + 1e-5f);
    float mu1 = a1 * (1.f / Cc);
    bc[2] = mu1; bc[3] = rsqrtf(b1 * (1.f / Cc) - mu1 * mu1 + 1e-5f);
  }
  __syncthreads();
  const float mu0 = bc[0], rs0 = bc[1], mu1 = bc[2], rs1 = bc[3];
#pragma unroll
  for (int r = 0; r < 2; ++r) {
    int i = threadIdx.x + r * 256;
    float4 g = ((const float4*)gamma)[i];
    float4 bb = ((const float4*)beta)[i];
    float4 v = cur[r];
    float mx = (v.x - mu0) * rs0 * g.x + bb.x;
    float my = (v.y - mu0) * rs0 * g.y + bb.y;
    float mz = (v.z - mu0) * rs0 * g.z + bb.z;
    float mw = (v.w - mu0) * rs0 * g.w + bb.w;
    if (t > 0) {
      float4 u = prv[r];
      mx = 0.5f * (mx + (u.x - mu1) * rs1 * g.x + bb.x);
      my = 0.5f * (my + (u.y - mu1) * rs1 * g.y + bb.y);
      mz = 0.5f * (mz + (u.z - mu1) * rs1 * g.z + bb.z);
      mw = 0.5f * (mw + (u.w - mu1) * rs1 * g.w + bb.w);
    } else {
      mx *= 0.5f; my *= 0.5f; mz *= 0.5f; mw *= 0.5f;
    }
    ushort4 o;
    o.x = f2bf(mx); o.y = f2bf(my); o.z = f2bf(mz); o.w = f2bf(mw);
    ((ushort4*)mix)[(size_t)m * 512 + i] = o;
  }
}

// ---------------- 256x128 BK=32 ring-3 pipelined GEMM, 2 blocks/CU ----------
// 256 threads = 4 waves (2 M x 2 N); wave tile 128x64; acc[8][4] f32x4 (AGPR).
// LDS: 3 ring buffers x (A 256x32 16KB + B 128x32 8KB) = 72 KiB -> 2 blk/CU.
// Swizzle: 16B slot s of row r stored at s ^ ((r>>1)&3); gload_lds dest linear,
// source col pre-swizzled, ds_read swizzled (0 conflicts, verified r3/r4).
// Ring-3 discipline: stage(t+2) targets buffer (t-1)%3 whose reads all
// completed before tile-t's top barrier (every ds_read is register-consumed
// by MFMAs before the wave reaches that barrier). vmcnt(6) gates own stage(t)
// (6 loads/thread/tile, <=12 outstanding); barrier extends to all threads.
template <bool STORE_BF16, bool ADD_BIAS>
__global__ __launch_bounds__(256, 2) void gemm_pipe(
    const unsigned short* __restrict__ A0p, long lda, long aStrideP,
    const unsigned short* __restrict__ B0p, long ldb, long bStrideP,
    void* c0, void* c1, void* c2, long ldc, int K,
    const float* __restrict__ bias, int nbx, int nby) {
  __shared__ unsigned short lds[3 * 12288];
  const int tid = threadIdx.x;
  const int nwg = gridDim.x;
  const int id = blockIdx.x;
  const int q = nwg >> 3;
  const int swz = (id & 7) * q + (id >> 3);
  const int per = nbx * nby;
  const int p = swz / per;
  const int r2 = swz - p * per;
  const int mblk = r2 / nbx;
  const int nblk = r2 - mblk * nbx;
  const unsigned short* A  = A0p + (long)p * aStrideP;
  const unsigned short* Bt = B0p + (long)p * bStrideP;
  void* Cout = (p == 0) ? c0 : (p == 1 ? c1 : c2);
  const long m0 = (long)mblk * 256, n0 = (long)nblk * 128;

  const int lane = tid & 63, wid = tid >> 6;
  const int wm = wid >> 1, wn = wid & 1;
  const int fr = lane & 15, fq = lane >> 4;

  // staging: thread covers rows (l*64 + tid>>2); LDS dest linear at tid*16B,
  // source logical slot = (tid&3) ^ ((row>>1)&3) = (tid&3) ^ ((tid>>3)&3).
  const int srow = tid >> 2;
  const int s_src = (tid & 3) ^ ((tid >> 3) & 3);
  const unsigned short* Ag = A + (m0 + srow) * lda + s_src * 8;
  const unsigned short* Bg = Bt + (n0 + srow) * ldb + s_src * 8;

  // read side: logical slot fq of row (..+fr) lives at slot fq ^ ((fr>>1)&3)
  const int swzs = fq ^ ((fr >> 1) & 3);
  const unsigned short* aBase = &lds[(wm * 128 + fr) * 32 + swzs * 8];
  const unsigned short* bBase = &lds[8192 + (wn * 64 + fr) * 32 + swzs * 8];

  f32x4 acc[8][4];
#pragma unroll
  for (int i = 0; i < 8; ++i)
#pragma unroll
    for (int j = 0; j < 4; ++j) acc[i][j] = (f32x4){0.f, 0.f, 0.f, 0.f};

  const int NT = K >> 5;

  auto stage = [&](int t, int buf) {
    unsigned short* dA = &lds[buf * 12288 + tid * 8];
    unsigned short* dB = &lds[buf * 12288 + 8192 + tid * 8];
    const long kt = (long)t * 32;
#pragma unroll
    for (int l = 0; l < 4; ++l)
      gload16(Ag + (long)(l * 64) * lda + kt, dA + l * 2048);
#pragma unroll
    for (int l = 0; l < 2; ++l)
      gload16(Bg + (long)(l * 64) * ldb + kt, dB + l * 2048);
  };

  // prologue: stage tiles 0,1 (12 loads/thread in flight)
  stage(0, 0); stage(1, 1);
  int bufR = 0, bufS = 2;

  for (int t = 0; t < NT; ++t) {
    if (t < NT - 1) asm volatile("s_waitcnt vmcnt(6)" ::: "memory");
    else            asm volatile("s_waitcnt vmcnt(0)" ::: "memory");
    __builtin_amdgcn_s_barrier();
    __builtin_amdgcn_sched_barrier(0);  // keep ds_reads below the barrier

    const unsigned short* ab = aBase + bufR * 12288;
    const unsigned short* bb = bBase + bufR * 12288;

    bf16x8 bf[4], af[8];
#pragma unroll
    for (int j = 0; j < 4; ++j) bf[j] = *(const bf16x8*)(bb + j * 512);
#pragma unroll
    for (int i = 0; i < 8; ++i) af[i] = *(const bf16x8*)(ab + i * 512);
    if (t + 2 < NT) stage(t + 2, bufS);
    __builtin_amdgcn_s_setprio(1);
#pragma unroll
    for (int i = 0; i < 8; ++i)
#pragma unroll
      for (int j = 0; j < 4; ++j)
        acc[i][j] = __builtin_amdgcn_mfma_f32_16x16x32_bf16(af[i], bf[j], acc[i][j], 0, 0, 0);
    __builtin_amdgcn_s_setprio(0);

    bufR = (bufR == 2) ? 0 : bufR + 1;
    bufS = (bufS == 2) ? 0 : bufS + 1;
  }

#pragma unroll
  for (int j = 0; j < 4; ++j) {
    const long col = n0 + wn * 64 + j * 16 + fr;
    const float bv = ADD_BIAS ? bias[col] : 0.0f;
#pragma unroll
    for (int i = 0; i < 8; ++i) {
      const long row0 = m0 + wm * 128 + i * 16 + fq * 4;
#pragma unroll
      for (int r = 0; r < 4; ++r) {
        float val = acc[i][j][r] + bv;
        if (STORE_BF16)
          ((unsigned short*)Cout)[(row0 + r) * ldc + col] = f2bf(val);
        else
          ((float*)Cout)[(row0 + r) * ldc + col] = val;
      }
    }
  }
}

// ---------------- split-K combine for G1 ------------------------------------
__global__ void addcvt_kernel(const float* __restrict__ p0, const float* __restrict__ p1,
                              unsigned short* __restrict__ o, int n4) {
  for (int i = blockIdx.x * blockDim.x + threadIdx.x; i < n4; i += gridDim.x * blockDim.x) {
    float4 a = ((const float4*)p0)[i];
    float4 b = ((const float4*)p1)[i];
    ushort4 r;
    r.x = f2bf(a.x + b.x); r.y = f2bf(a.y + b.y);
    r.z = f2bf(a.z + b.z); r.w = f2bf(a.w + b.w);
    ((ushort4*)o)[i] = r;
  }
}

// ---------------- chunked scan ---------------------------------------------
__global__ void scan_phaseA(const unsigned short* __restrict__ k, const unsigned short* __restrict__ v,
                            const float* __restrict__ decay, float* __restrict__ hend) {
  const int g = blockIdx.x * 256 + threadIdx.x;
  const int c = g & (Cc - 1);
  const int j = (g >> 11) & (NCH - 1);
  const int b = g >> 16;
  const float d = decay[c];
  size_t base = ((size_t)(b * Tt + j * CLEN)) * Cc + c;
  float h = 0.f;
#pragma unroll 8
  for (int s = 0; s < CLEN; ++s) {
    size_t idx = base + (size_t)s * Cc;
    float kv = bf2f(k[idx]) * bf2f(v[idx]);
    h = fmaf(d, h, kv);
  }
  hend[(size_t)(b * NCH + j) * Cc + c] = h;
}

__global__ void scan_combine(const float* __restrict__ hend, const float* __restrict__ h0,
                             const float* __restrict__ decayL, float* __restrict__ Hin,
                             float* __restrict__ hfinal) {
  const int g = blockIdx.x * 256 + threadIdx.x;
  const int c = g & (Cc - 1);
  float H = h0[g];
  const float dl = decayL[c];
  const int b = g >> 11;
  for (int j = 0; j < NCH; ++j) {
    size_t idx = (size_t)(b * NCH + j) * Cc + c;
    Hin[idx] = H;
    H = fmaf(dl, H, hend[idx]);
  }
  hfinal[g] = H;
}

__global__ void scan_phaseB(const unsigned short* __restrict__ q, const unsigned short* __restrict__ k,
                            const unsigned short* __restrict__ v, const float* __restrict__ decay,
                            const float* __restrict__ Hin, unsigned short* __restrict__ ys) {
  const int g = blockIdx.x * 256 + threadIdx.x;
  const int c = g & (Cc - 1);
  const int j = (g >> 11) & (NCH - 1);
  const int b = g >> 16;
  const float d = decay[c];
  float h = Hin[(size_t)(b * NCH + j) * Cc + c];
  size_t base = ((size_t)(b * Tt + j * CLEN)) * Cc + c;
#pragma unroll 4
  for (int s = 0; s < CLEN; ++s) {
    size_t idx = base + (size_t)s * Cc;
    float kv = bf2f(k[idx]) * bf2f(v[idx]);
    h = fmaf(d, h, kv);
    float qq = bf2f(q[idx]);
    float sg = 1.f / (1.f + expf(-qq));
    ys[idx] = f2bf(sg * h);
  }
}

// ---------------- launch ----------------------------------------------------
extern "C" void kernel_launch(void* const* d_in, const int* in_sizes, int n_in,
                              void* d_out, int out_size, void* d_ws, size_t ws_size,
                              hipStream_t stream) {
  const float* x   = (const float*)d_in[0];
  const float* h0  = (const float*)d_in[1];
  const float* gam = (const float*)d_in[2];
  const float* bet = (const float*)d_in[3];
  const float* wqa = (const float*)d_in[4];
  const float* wqb = (const float*)d_in[5];
  const float* wka = (const float*)d_in[6];
  const float* wkb = (const float*)d_in[7];
  const float* wva = (const float*)d_in[8];
  const float* wvb = (const float*)d_in[9];
  const float* ow  = (const float*)d_in[10];
  const float* ob  = (const float*)d_in[11];
  const float* td  = (const float*)d_in[12];
  float* out = (float*)d_out;

  char* ws = (char*)d_ws;
  unsigned short* waT   = (unsigned short*)(ws + 0);          //  3,145,728
  unsigned short* wbT   = (unsigned short*)(ws + 3145728);    //  3,145,728
  unsigned short* owT   = (unsigned short*)(ws + 6291456);    //  8,388,608
  float*          decay = (float*)(ws + 14680064);
  float*          decayL= (float*)(ws + 14688256);
  unsigned short* mixb  = (unsigned short*)(ws + 14761984);   // 33,554,432 (reused as ys)
  unsigned short* tmp   = (unsigned short*)(ws + 48316416);   // 12,582,912
  unsigned short* vp    = (unsigned short*)(ws + 60899328);   // 33,554,432
  float*          hend  = (float*)(ws + 94453760);
  float*          Hin   = (float*)(ws + 95502336);
  // staged in d_out (dead before overwritten): G1 f32 partials, then q,k bf16
  float* P0 = (float*)d_out;                                  // 25.2 MB
  float* P1 = P0 + (size_t)Mrows * 768;                       // 25.2 MB
  unsigned short* qp = (unsigned short*)d_out;
  unsigned short* kp = qp + (size_t)Mrows * Cc;
  float* hfinal = out + (size_t)Mrows * Cc;
  unsigned short* ysb = mixb;

  prep_weights<<<1024, 256, 0, stream>>>(wqa, wka, wva, wqb, wkb, wvb, ow, td,
                                         waT, wbT, owT, decay, decayL);
  lnmix_kernel<<<Mrows, 256, 0, stream>>>(x, gam, bet, mixb);

  // G1 split-K x2: P_p[8192][768] = mix[:, p*1024:(p+1)*1024] @ waT_half
  // (384 blocks: nbx=6, nby=32, p = K-half)
  gemm_pipe<false, false><<<384, 256, 0, stream>>>(
      mixb, Cc, 1024, waT, Cc, 1024,
      P0, P1, nullptr, 768, 1024, nullptr, 6, 32);
  addcvt_kernel<<<1024, 256, 0, stream>>>(P0, P1, tmp, Mrows * 768 / 4);

  // G2 grouped: q/k/v[8192][2048] = tmp_p @ w_b_p   (1536 blocks)
  gemm_pipe<true, false><<<1536, 256, 0, stream>>>(
      tmp, 768, 256, wbT, Rr, (long)Cc * Rr,
      qp, kp, vp, Cc, Rr, nullptr, 16, 32);

  scan_phaseA<<<(Bb * NCH * Cc) / 256, 256, 0, stream>>>(kp, vp, decay, hend);
  scan_combine<<<(Bb * Cc) / 256, 256, 0, stream>>>(hend, h0, decayL, Hin, hfinal);
  scan_phaseB<<<(Bb * NCH * Cc) / 256, 256, 0, stream>>>(qp, kp, vp, decay, Hin, ysb);

  // Gout: out = ys @ out_w^T + out_b   (512 blocks)
  gemm_pipe<false, true><<<512, 256, 0, stream>>>(
      ysb, Cc, 0, owT, Cc, 0,
      out, out, out, Cc, Cc, ob, 16, 32);
}